// Round 2
// baseline (220.643 us; speedup 1.0000x reference)
//
#include <hip/hip_runtime.h>
#include <hip/hip_bf16.h>
#include <stdint.h>

#define IN_C 256
#define OUT_C 256
#define HH 56
#define WW 56
#define NB 32
#define HP 58
#define WP 58

#define BM 128   // pixels per block
#define BN 128   // output channels per block
#define BK 64    // K elements per step
#define KSTEPS 36  // 9 (kh,kw) * (256/64)

typedef __attribute__((ext_vector_type(8))) short short8;
typedef __attribute__((ext_vector_type(4))) float float4_t;

typedef const __attribute__((address_space(1))) unsigned int guint_t;
typedef __attribute__((address_space(3))) unsigned int luint_t;

__device__ __forceinline__ unsigned short f2bf(float f) {
    union { float f; unsigned u; } v; v.f = f;
    unsigned r = v.u + 0x7FFF + ((v.u >> 16) & 1);   // RNE
    return (unsigned short)(r >> 16);
}

// async global->LDS, 16B per lane. LDS dest is wave-uniform base + lane*16.
__device__ __forceinline__ void gload16(void* lds, const void* g) {
    __builtin_amdgcn_global_load_lds((guint_t*)g, (luint_t*)lds, 16, 0, 0);
}

// ---------------- pre-pass 1: NCHW f32 -> padded NHWC bf16 ----------------
// block = (n, h_padded). LDS transpose [w][ic] stride 257 (conflict-free writes).
__global__ __launch_bounds__(256) void pad_nhwc(const float* __restrict__ x,
                                                unsigned short* __restrict__ xpad) {
    __shared__ float lds[WW * 257];
    int bid = blockIdx.x;
    int n = bid / HP, h = bid % HP;
    unsigned short* dstRow = xpad + (size_t)(n * HP + h) * WP * IN_C;
    bool hin = (h >= 1 && h <= HH);
    if (hin) {
        const float* src = x + (size_t)n * IN_C * (HH * WW) + (h - 1) * WW;
        for (int e = threadIdx.x; e < IN_C * WW; e += 256) {
            int ic = e / WW, w = e - ic * WW;
            lds[w * 257 + ic] = src[(size_t)ic * (HH * WW) + w];
        }
    }
    __syncthreads();
    for (int e = threadIdx.x; e < WP * (IN_C / 8); e += 256) {
        int wo = e / (IN_C / 8);
        int icc = e - wo * (IN_C / 8);
        short8 v = {0, 0, 0, 0, 0, 0, 0, 0};
        if (hin && wo >= 1 && wo <= WW) {
            const float* p = &lds[(wo - 1) * 257 + icc * 8];
#pragma unroll
            for (int j = 0; j < 8; ++j) v[j] = (short)f2bf(p[j]);
        }
        *(short8*)(dstRow + wo * IN_C + icc * 8) = v;
    }
}

// ---------------- pre-pass 2: OIHW f32 -> [oc][kh][kw][ic] bf16 ----------------
__global__ __launch_bounds__(256) void wconv(const float* __restrict__ w,
                                             unsigned short* __restrict__ wt) {
    int o = blockIdx.x * 256 + threadIdx.x;      // flat over [oc][khw][ic]
    if (o < OUT_C * 2304) {
        int oc = o / 2304;
        int rem = o - oc * 2304;
        int khw = rem / 256;
        int ic = rem - khw * 256;
        wt[o] = f2bf(w[(size_t)oc * 2304 + ic * 9 + khw]);
    }
}

// ---------------- main: implicit-GEMM conv, bf16 MFMA ----------------
// C[oc][m] = sum_k W[oc][k] * X[k][m],  k ordered (kh,kw,ic), m = (n,oh,ow)
__global__ __launch_bounds__(256) void conv_mfma(const unsigned short* __restrict__ xpad,
                                                 const unsigned short* __restrict__ wt,
                                                 float* __restrict__ out) {
    __shared__ unsigned short Xs[BM * BK];   // [m][k-chunk swizzled]
    __shared__ unsigned short Ws[BN * BK];   // [oc][k-chunk swizzled]

    const int tid = threadIdx.x;
    const int lane = tid & 63;
    const int wid = tid >> 6;
    const int wr = wid >> 1;   // oc half (0/1)
    const int wc = wid & 1;    // pixel half (0/1)
    const int m0 = blockIdx.x * BM;
    const int oc0 = blockIdx.y * BN;

    // staging: thread stages 16B chunk e16 = t*256+tid; row = e16>>3, cc = tid&7.
    // swizzle: LDS physical [row][cc] holds logical chunk cc ^ (row&7)  (rule #21:
    // linear LDS dest + inverse-swizzled global source + swizzled ds_read).
    const int ccg = (tid & 7) ^ ((tid >> 3) & 7);
    const unsigned short* gx[4];
    const unsigned short* gw[4];
#pragma unroll
    for (int t = 0; t < 4; ++t) {
        int row = t * 32 + (tid >> 3);
        int m = m0 + row;
        int n = m / (HH * WW);
        int r = m - n * (HH * WW);
        int oh = r / WW, ow = r - oh * WW;
        gx[t] = xpad + (size_t)((n * HP + oh) * WP + ow) * IN_C + ccg * 8;
        gw[t] = wt + (size_t)(oc0 + row) * 2304 + ccg * 8;
    }

    float4_t acc[4][4];
#pragma unroll
    for (int a = 0; a < 4; ++a)
#pragma unroll
        for (int b = 0; b < 4; ++b) acc[a][b] = {0.f, 0.f, 0.f, 0.f};

    for (int s = 0; s < KSTEPS; ++s) {
        int khw = s >> 2;
        int ic0 = (s & 3) * BK;
        int kh = khw / 3, kw = khw - kh * 3;
        size_t xoff = (size_t)(kh * WP + kw) * IN_C + ic0;
        size_t woff = (size_t)khw * IN_C + ic0;

        __syncthreads();   // previous step's LDS reads complete
#pragma unroll
        for (int t = 0; t < 4; ++t) {
            gload16(&Xs[(t * 256 + tid) * 8], gx[t] + xoff);
            gload16(&Ws[(t * 256 + tid) * 8], gw[t] + woff);
        }
        __syncthreads();   // staging complete (vmcnt drained at barrier)

#pragma unroll
        for (int ks = 0; ks < 2; ++ks) {
            short8 af[4], bfr[4];
#pragma unroll
            for (int a = 0; a < 4; ++a) {
                int row = wr * 64 + a * 16 + (lane & 15);
                int c = ((lane >> 4) + ks * 4) ^ (row & 7);
                af[a] = *(const short8*)&Ws[row * BK + c * 8];
            }
#pragma unroll
            for (int b = 0; b < 4; ++b) {
                int row = wc * 64 + b * 16 + (lane & 15);
                int c = ((lane >> 4) + ks * 4) ^ (row & 7);
                bfr[b] = *(const short8*)&Xs[row * BK + c * 8];
            }
#pragma unroll
            for (int a = 0; a < 4; ++a)
#pragma unroll
                for (int b = 0; b < 4; ++b)
                    acc[a][b] = __builtin_amdgcn_mfma_f32_16x16x32_bf16(
                        af[a], bfr[b], acc[a][b], 0, 0, 0);
        }
    }

    // epilogue: D col = lane&15 -> pixel, row = (lane>>4)*4+reg -> oc  [m89/m91]
#pragma unroll
    for (int b = 0; b < 4; ++b) {
        int mf = m0 + wc * 64 + b * 16 + (lane & 15);
        int n = mf / (HH * WW);
        int pix = mf - n * (HH * WW);
        float* op = out + (size_t)n * (OUT_C * HH * WW) + pix;
#pragma unroll
        for (int a = 0; a < 4; ++a) {
            int oc = oc0 + wr * 64 + a * 16 + ((lane >> 4) << 2);
#pragma unroll
            for (int reg = 0; reg < 4; ++reg) {
                op[(size_t)(oc + reg) * (HH * WW)] = acc[a][b][reg];
            }
        }
    }
}

extern "C" void kernel_launch(void* const* d_in, const int* in_sizes, int n_in,
                              void* d_out, int out_size, void* d_ws, size_t ws_size,
                              hipStream_t stream) {
    const float* x = (const float*)d_in[0];
    const float* wgt = (const float*)d_in[1];
    float* out = (float*)d_out;

    unsigned short* xpad = (unsigned short*)d_ws;                       // 55.1 MB
    size_t xpad_bytes = (size_t)NB * HP * WP * IN_C * 2;
    unsigned short* wtx = (unsigned short*)((char*)d_ws + xpad_bytes);  // 1.18 MB

    hipLaunchKernelGGL(pad_nhwc, dim3(NB * HP), dim3(256), 0, stream, x, xpad);
    hipLaunchKernelGGL(wconv, dim3((OUT_C * 2304) / 256), dim3(256), 0, stream, wgt, wtx);
    hipLaunchKernelGGL(conv_mfma, dim3((NB * HH * WW) / BM, OUT_C / BN), dim3(256), 0,
                       stream, xpad, wtx, out);
}

// Round 3
// 178.700 us; speedup vs baseline: 1.2347x; 1.2347x over previous
//
#include <hip/hip_runtime.h>
#include <hip/hip_bf16.h>
#include <stdint.h>

#define IN_C 256
#define OUT_C 256
#define HH 56
#define WW 56
#define NB 32
#define HP 58
#define WP 58

#define BM 256        // pixels per block
#define BK 64         // K per tile
#define NKT 36        // 9 taps * (256/64)
#define NTILE 392     // 100352 / 256

typedef __attribute__((ext_vector_type(8))) short short8;
typedef __attribute__((ext_vector_type(4))) float float4_t;

typedef const __attribute__((address_space(1))) unsigned int guint_t;
typedef __attribute__((address_space(3))) unsigned int luint_t;

__device__ __forceinline__ unsigned short f2bf(float f) {
    union { float f; unsigned u; } v; v.f = f;
    unsigned r = v.u + 0x7FFF + ((v.u >> 16) & 1);   // RNE
    return (unsigned short)(r >> 16);
}

__device__ __forceinline__ void gload16(void* lds, const void* g) {
    __builtin_amdgcn_global_load_lds((guint_t*)g, (luint_t*)lds, 16, 0, 0);
}

// ---------------- pre-pass 1: NCHW f32 -> padded NHWC bf16 ----------------
__global__ __launch_bounds__(256) void pad_nhwc(const float* __restrict__ x,
                                                unsigned short* __restrict__ xpad) {
    __shared__ float lds[WW * 257];
    int bid = blockIdx.x;
    int n = bid / HP, h = bid % HP;
    unsigned short* dstRow = xpad + (size_t)(n * HP + h) * WP * IN_C;
    bool hin = (h >= 1 && h <= HH);
    if (hin) {
        const float* src = x + (size_t)n * IN_C * (HH * WW) + (h - 1) * WW;
        for (int e = threadIdx.x; e < IN_C * WW; e += 256) {
            int ic = e / WW, w = e - ic * WW;
            lds[w * 257 + ic] = src[(size_t)ic * (HH * WW) + w];
        }
    }
    __syncthreads();
    for (int e = threadIdx.x; e < WP * (IN_C / 8); e += 256) {
        int wo = e / (IN_C / 8);
        int icc = e - wo * (IN_C / 8);
        short8 v = {0, 0, 0, 0, 0, 0, 0, 0};
        if (hin && wo >= 1 && wo <= WW) {
            const float* p = &lds[(wo - 1) * 257 + icc * 8];
#pragma unroll
            for (int j = 0; j < 8; ++j) v[j] = (short)f2bf(p[j]);
        }
        *(short8*)(dstRow + wo * IN_C + icc * 8) = v;
    }
}

// ---------------- pre-pass 2: OIHW f32 -> [oc][kh][kw][ic] bf16 ----------------
__global__ __launch_bounds__(256) void wconv(const float* __restrict__ w,
                                             unsigned short* __restrict__ wt) {
    int o = blockIdx.x * 256 + threadIdx.x;
    if (o < OUT_C * 2304) {
        int oc = o / 2304;
        int rem = o - oc * 2304;
        int khw = rem / 256;
        int ic = rem - khw * 256;
        wt[o] = f2bf(w[(size_t)oc * 2304 + ic * 9 + khw]);
    }
}

// ---------------- main: 8-wave 256x256 4-phase pipelined implicit-GEMM ----------------
// C[oc][pix] += W[oc][k] * X[pix][k],  k = (kh,kw,ic), 36 K-tiles of 64
__global__ __launch_bounds__(512, 2) void conv_mfma8(const unsigned short* __restrict__ xpad,
                                                     const unsigned short* __restrict__ wt,
                                                     float* __restrict__ out) {
    // [0..1] = W double-buffer, [2..3] = X double-buffer; each 256 rows x 64 k (32 KB)
    __shared__ unsigned short lds[4][16384];

    const int tid = threadIdx.x;
    const int lane = tid & 63;
    const int wid = tid >> 6;
    const int wm = wid >> 2;    // oc half (rows wm*128..)
    const int wn = wid & 3;     // pixel quarter (cols wn*64..)

    const int bid = blockIdx.x;
    const int tile = (bid & 7) * 49 + (bid >> 3);   // bijective XCD swizzle (392 = 8*49)
    const int m0 = tile * BM;

    // ---- staging source addresses: thread stages physical 16B chunk p = t*512+tid ----
    // row = p>>3, physChunk = p&7; logical chunk c = phys ^ (row&7)  (rule #21)
    const unsigned short* gw[4];
    const unsigned short* gx[4];
    {
        const int prow = tid >> 3;
        const int ppc = tid & 7;
#pragma unroll
        for (int t = 0; t < 4; ++t) {
            int row = t * 64 + prow;
            int c = ppc ^ (row & 7);
            gw[t] = wt + (size_t)row * 2304 + c * 8;
            int m = m0 + row;
            int n = m / (HH * WW);
            int r = m - n * (HH * WW);
            int oh = r / WW, ow = r - oh * WW;
            gx[t] = xpad + (size_t)((n * HP + oh) * WP + ow) * IN_C + c * 8;
        }
    }

    // ---- fragment ds_read addressing ----
    const int rlo = lane & 15;
    const int kq = lane >> 4;
    const int sw = rlo & 7;
    const int baseA = (wm * 128 + rlo) * 64;
    const int baseB = (wn * 64 + rlo) * 64;
    const int o0 = (kq ^ sw) * 8;
    const int o1 = ((kq + 4) ^ sw) * 8;

    float4_t acc[8][4];
#pragma unroll
    for (int f = 0; f < 8; ++f)
#pragma unroll
        for (int x = 0; x < 4; ++x) acc[f][x] = {0.f, 0.f, 0.f, 0.f};

    // ---- prologue: stage K-tile 0 into buffers 0 ----
#pragma unroll
    for (int t = 0; t < 4; ++t) gload16(&lds[0][(t * 512 + tid) * 8], gw[t]);
#pragma unroll
    for (int t = 0; t < 4; ++t) gload16(&lds[2][(t * 512 + tid) * 8], gx[t]);
    asm volatile("s_waitcnt vmcnt(0)" ::: "memory");
    __builtin_amdgcn_s_barrier();
    __builtin_amdgcn_sched_barrier(0);

    for (int kt = 0; kt < NKT; ++kt) {
        const int cur = kt & 1;
        const int nxt = cur ^ 1;
        const unsigned short* Wb = lds[cur];
        const unsigned short* Xb = lds[2 + cur];

        const int kt1 = kt + 1;
        const int khw1 = kt1 >> 2;
        const int ic01 = (kt1 & 3) * 64;
        const int kh1 = khw1 / 3, kw1 = khw1 - kh1 * 3;
        const size_t woff1 = (size_t)khw1 * 256 + ic01;
        const size_t xoff1 = (size_t)(kh1 * WP + kw1) * IN_C + ic01;
        const bool doStage = (kt1 < NKT);

        short8 a[8], b[8];

        // ======== phase 0: ds_read A-frags 0-3 + all B-frags; stage W(kt+1) ========
#pragma unroll
        for (int ff = 0; ff < 4; ++ff) {
            a[ff * 2 + 0] = *(const short8*)&Wb[baseA + ff * 1024 + o0];
            a[ff * 2 + 1] = *(const short8*)&Wb[baseA + ff * 1024 + o1];
        }
#pragma unroll
        for (int ff = 0; ff < 4; ++ff) {
            b[ff * 2 + 0] = *(const short8*)&Xb[baseB + ff * 1024 + o0];
            b[ff * 2 + 1] = *(const short8*)&Xb[baseB + ff * 1024 + o1];
        }
        if (doStage) {
#pragma unroll
            for (int t = 0; t < 4; ++t)
                gload16(&lds[nxt][(t * 512 + tid) * 8], gw[t] + woff1);
        }
        __builtin_amdgcn_s_barrier();
        asm volatile("s_waitcnt lgkmcnt(0)" ::: "memory");
        __builtin_amdgcn_sched_barrier(0);
        __builtin_amdgcn_s_setprio(1);
#pragma unroll
        for (int ff = 0; ff < 2; ++ff)
#pragma unroll
            for (int x = 0; x < 4; ++x) {
                acc[ff][x] = __builtin_amdgcn_mfma_f32_16x16x32_bf16(a[ff * 2 + 0], b[x * 2 + 0], acc[ff][x], 0, 0, 0);
                acc[ff][x] = __builtin_amdgcn_mfma_f32_16x16x32_bf16(a[ff * 2 + 1], b[x * 2 + 1], acc[ff][x], 0, 0, 0);
            }
        __builtin_amdgcn_s_setprio(0);
        __builtin_amdgcn_s_barrier();

        // ======== phase 1: stage X(kt+1); MFMA A-frags 2-3 ========
        if (doStage) {
#pragma unroll
            for (int t = 0; t < 4; ++t)
                gload16(&lds[2 + nxt][(t * 512 + tid) * 8], gx[t] + xoff1);
        }
        __builtin_amdgcn_s_barrier();
        __builtin_amdgcn_s_setprio(1);
#pragma unroll
        for (int ff = 2; ff < 4; ++ff)
#pragma unroll
            for (int x = 0; x < 4; ++x) {
                acc[ff][x] = __builtin_amdgcn_mfma_f32_16x16x32_bf16(a[ff * 2 + 0], b[x * 2 + 0], acc[ff][x], 0, 0, 0);
                acc[ff][x] = __builtin_amdgcn_mfma_f32_16x16x32_bf16(a[ff * 2 + 1], b[x * 2 + 1], acc[ff][x], 0, 0, 0);
            }
        __builtin_amdgcn_s_setprio(0);
        __builtin_amdgcn_s_barrier();

        // ======== phase 2: ds_read A-frags 4-7; MFMA -> acc[4..5] ========
#pragma unroll
        for (int ff = 0; ff < 4; ++ff) {
            a[ff * 2 + 0] = *(const short8*)&Wb[baseA + 4096 + ff * 1024 + o0];
            a[ff * 2 + 1] = *(const short8*)&Wb[baseA + 4096 + ff * 1024 + o1];
        }
        __builtin_amdgcn_s_barrier();
        asm volatile("s_waitcnt lgkmcnt(0)" ::: "memory");
        __builtin_amdgcn_sched_barrier(0);
        __builtin_amdgcn_s_setprio(1);
#pragma unroll
        for (int ff = 0; ff < 2; ++ff)
#pragma unroll
            for (int x = 0; x < 4; ++x) {
                acc[4 + ff][x] = __builtin_amdgcn_mfma_f32_16x16x32_bf16(a[ff * 2 + 0], b[x * 2 + 0], acc[4 + ff][x], 0, 0, 0);
                acc[4 + ff][x] = __builtin_amdgcn_mfma_f32_16x16x32_bf16(a[ff * 2 + 1], b[x * 2 + 1], acc[4 + ff][x], 0, 0, 0);
            }
        __builtin_amdgcn_s_setprio(0);
        __builtin_amdgcn_s_barrier();

        // ======== phase 3: MFMA -> acc[6..7]; drain stage loads; tile barrier ========
        __builtin_amdgcn_s_setprio(1);
#pragma unroll
        for (int ff = 2; ff < 4; ++ff)
#pragma unroll
            for (int x = 0; x < 4; ++x) {
                acc[4 + ff][x] = __builtin_amdgcn_mfma_f32_16x16x32_bf16(a[ff * 2 + 0], b[x * 2 + 0], acc[4 + ff][x], 0, 0, 0);
                acc[4 + ff][x] = __builtin_amdgcn_mfma_f32_16x16x32_bf16(a[ff * 2 + 1], b[x * 2 + 1], acc[4 + ff][x], 0, 0, 0);
            }
        __builtin_amdgcn_s_setprio(0);
        asm volatile("s_waitcnt vmcnt(0)" ::: "memory");
        __builtin_amdgcn_s_barrier();
        __builtin_amdgcn_sched_barrier(0);
    }

    // ---- epilogue: C col = lane&15 -> pixel, row = (lane>>4)*4+reg -> oc ----
#pragma unroll
    for (int x = 0; x < 4; ++x) {
        int mf = m0 + wn * 64 + x * 16 + (lane & 15);
        int n = mf / (HH * WW);
        int pix = mf - n * (HH * WW);
        float* op = out + (size_t)n * (OUT_C * HH * WW) + pix;
#pragma unroll
        for (int f = 0; f < 8; ++f) {
            int oc = wm * 128 + f * 16 + ((lane >> 4) << 2);
#pragma unroll
            for (int reg = 0; reg < 4; ++reg)
                op[(size_t)(oc + reg) * (HH * WW)] = acc[f][x][reg];
        }
    }
}

extern "C" void kernel_launch(void* const* d_in, const int* in_sizes, int n_in,
                              void* d_out, int out_size, void* d_ws, size_t ws_size,
                              hipStream_t stream) {
    const float* x = (const float*)d_in[0];
    const float* wgt = (const float*)d_in[1];
    float* out = (float*)d_out;

    unsigned short* xpad = (unsigned short*)d_ws;                       // 55.1 MB
    size_t xpad_bytes = (size_t)NB * HP * WP * IN_C * 2;
    unsigned short* wtx = (unsigned short*)((char*)d_ws + xpad_bytes);  // 1.18 MB

    hipLaunchKernelGGL(pad_nhwc, dim3(NB * HP), dim3(256), 0, stream, x, xpad);
    hipLaunchKernelGGL(wconv, dim3((OUT_C * 2304) / 256), dim3(256), 0, stream, wgt, wtx);
    hipLaunchKernelGGL(conv_mfma8, dim3(NTILE), dim3(512), 0, stream, xpad, wtx, out);
}